// Round 1
// baseline (2264.926 us; speedup 1.0000x reference)
//
#include <hip/hip_runtime.h>
#include <math.h>

#define NPTS 12288
#define DIM 64
#define KNN 85
#define KSEL 86          // 85 neighbors + self
#define SAMPLE 2000
#define SSTRIDE 6        // deterministic sample: idx = 6*p, p in [0,2000)
#define GAMMA 0.5f

// acc layout (doubles in d_ws):
// [0]=sum(ed) [1]=sum(cd) [2]=sum(ed^2) [3]=sum(cd^2) [4]=sum(ed*cd) [5]=sum(local)

__global__ __launch_bounds__(256) void pearson_kernel(
    const float* __restrict__ emb, const float* __restrict__ coord,
    double* __restrict__ acc) {
  __shared__ float Ep[16][DIM];
  __shared__ float Eq[16][DIM];
  __shared__ float Cp[16][3];
  __shared__ float Cq[16][3];
  __shared__ double red[256];

  int tx = threadIdx.x, ty = threadIdx.y;
  int t = ty * 16 + tx;
  int p0 = blockIdx.y * 16, q0 = blockIdx.x * 16;

  // stage 16 p-rows and 16 q-rows of embeddings (sampled with stride 6)
  for (int e = t; e < 16 * DIM; e += 256) {
    int r = e / DIM, k = e % DIM;
    Ep[r][k] = emb[(size_t)((p0 + r) * SSTRIDE) * DIM + k];
    Eq[r][k] = emb[(size_t)((q0 + r) * SSTRIDE) * DIM + k];
  }
  if (t < 16 * 3) {
    int r = t / 3, c = t % 3;
    Cp[r][c] = coord[(size_t)((p0 + r) * SSTRIDE) * 3 + c];
    Cq[r][c] = coord[(size_t)((q0 + r) * SSTRIDE) * 3 + c];
  }
  __syncthreads();

  // one (p,q) pair per thread
  float s = 0.0f;
  for (int k = 0; k < DIM; ++k) {
    float d = Ep[ty][k] - Eq[tx][k];
    s += d * d;
  }
  float ed = sqrtf(fmaxf(s, 0.0f));
  float d0 = Cp[ty][0] - Cq[tx][0];
  float d1 = Cp[ty][1] - Cq[tx][1];
  float d2 = Cp[ty][2] - Cq[tx][2];
  float cd = sqrtf(fmaxf(d0 * d0 + d1 * d1 + d2 * d2, 0.0f));

  double vals[5];
  vals[0] = (double)ed;
  vals[1] = (double)cd;
  vals[2] = (double)ed * (double)ed;
  vals[3] = (double)cd * (double)cd;
  vals[4] = (double)ed * (double)cd;

  for (int v = 0; v < 5; ++v) {
    red[t] = vals[v];
    __syncthreads();
    for (int s2 = 128; s2 > 0; s2 >>= 1) {
      if (t < s2) red[t] += red[t + s2];
      __syncthreads();
    }
    if (t == 0) atomicAdd(&acc[v], red[0]);
    __syncthreads();
  }
}

__global__ __launch_bounds__(256) void knn_kernel(
    const float* __restrict__ emb, const float* __restrict__ coord,
    double* __restrict__ acc) {
  __shared__ float d2s[NPTS];        // 48 KiB
  __shared__ unsigned hist[256];
  __shared__ unsigned sb[2];
  __shared__ float embi[DIM];
  __shared__ double red[256];

  int i = blockIdx.x;
  int tid = threadIdx.x;

  float cx = coord[(size_t)i * 3 + 0];
  float cy = coord[(size_t)i * 3 + 1];
  float cz = coord[(size_t)i * 3 + 2];

  // all squared distances from point i into LDS
  for (int j = tid; j < NPTS; j += 256) {
    float dx = cx - coord[(size_t)j * 3 + 0];
    float dy = cy - coord[(size_t)j * 3 + 1];
    float dz = cz - coord[(size_t)j * 3 + 2];
    d2s[j] = dx * dx + dy * dy + dz * dz;
  }
  if (tid < DIM) embi[tid] = emb[(size_t)i * DIM + tid];
  __syncthreads();

  // radix-select the KSEL-th smallest d2 (float bits are monotonic for >=0)
  unsigned prefix = 0;
  unsigned want = KSEL;
  for (int pass = 0; pass < 4; ++pass) {
    int shift = 24 - 8 * pass;
    hist[tid] = 0;
    __syncthreads();
    unsigned mask = pass ? (0xFFFFFFFFu << (32 - 8 * pass)) : 0u;
    for (int j = tid; j < NPTS; j += 256) {
      unsigned u = __float_as_uint(d2s[j]);
      if ((u & mask) == prefix) atomicAdd(&hist[(u >> shift) & 0xFFu], 1u);
    }
    __syncthreads();
    if (tid == 0) {
      unsigned cum = 0;
      for (unsigned b = 0; b < 256; ++b) {
        unsigned c = hist[b];
        if (cum + c >= want) { sb[0] = b; sb[1] = cum; break; }
        cum += c;
      }
    }
    __syncthreads();
    prefix |= sb[0] << shift;
    want -= sb[1];
    __syncthreads();
  }
  float r = __uint_as_float(prefix);  // exact value of the 86th-smallest d2

  // accumulate loss over the 85 neighbors (d2 <= r, j != i)
  double lsum = 0.0;
  for (int j = tid; j < NPTS; j += 256) {
    float dj = d2s[j];
    if (j != i && dj <= r) {
      float td = sqrtf(dj);
      const float* ej = emb + (size_t)j * DIM;
      float s = 0.0f;
      for (int k = 0; k < DIM; ++k) {
        float d = embi[k] - ej[k];
        s += d * d;
      }
      float pd = sqrtf(fmaxf(s, 0.0f));
      float diff = pd - td;
      lsum += (double)(diff * diff * expf(-GAMMA * td));
    }
  }
  red[tid] = lsum;
  __syncthreads();
  for (int s2 = 128; s2 > 0; s2 >>= 1) {
    if (tid < s2) red[tid] += red[tid + s2];
    __syncthreads();
  }
  if (tid == 0) atomicAdd(&acc[5], red[0]);
}

__global__ void finalize_kernel(const double* __restrict__ acc,
                                float* __restrict__ out) {
  double M = (double)SAMPLE * (double)SAMPLE;
  double med = acc[0] / M, mcd = acc[1] / M;
  double ve = acc[2] / M - med * med;
  double vc = acc[3] / M - mcd * mcd;
  double es = sqrt(ve + 1e-8);
  double cs = sqrt(vc + 1e-8);
  double cov = acc[4] / M - med * mcd;
  double pearson = cov / (es * cs + 1e-8);
  double local = acc[5] / ((double)NPTS * (double)KNN);
  out[0] = (float)((1.0 - pearson) + 0.5 * local);
}

extern "C" void kernel_launch(void* const* d_in, const int* in_sizes, int n_in,
                              void* d_out, int out_size, void* d_ws, size_t ws_size,
                              hipStream_t stream) {
  const float* emb = (const float*)d_in[0];    // (12288, 64) f32
  const float* coord = (const float*)d_in[1];  // (12288, 3) f32
  double* acc = (double*)d_ws;

  hipMemsetAsync(d_ws, 0, 6 * sizeof(double), stream);

  dim3 bp(16, 16);
  dim3 gp(SAMPLE / 16, SAMPLE / 16);  // 125 x 125
  pearson_kernel<<<gp, bp, 0, stream>>>(emb, coord, acc);

  knn_kernel<<<NPTS, 256, 0, stream>>>(emb, coord, acc);

  finalize_kernel<<<1, 1, 0, stream>>>(acc, (float*)d_out);
}

// Round 2
// 983.734 us; speedup vs baseline: 2.3024x; 2.3024x over previous
//
#include <hip/hip_runtime.h>
#include <math.h>

#define NPTS 12288
#define DIM 64
#define KNN 85
#define KSEL 86          // 85 neighbors + self
#define SAMPLE 2000
#define SSTRIDE 6        // deterministic sample: idx = 6*p, p in [0,2000)
#define GAMMA 0.5f
#define ITERS (NPTS / 256)   // 48 d2 values per thread, kept in VGPRs
#define TS 32                // pearson tile

// acc layout (doubles in d_ws):
// [0]=sum(ed) [1]=sum(cd) [2]=sum(ed^2) [3]=sum(cd^2) [4]=sum(ed*cd) [5]=sum(local)

__global__ __launch_bounds__(256) void pearson_kernel(
    const float* __restrict__ emb, const float* __restrict__ coord,
    double* __restrict__ acc) {
  __shared__ float Ep[TS][DIM + 1];   // +1 pad: rows land in distinct banks
  __shared__ float Eq[TS][DIM + 1];
  __shared__ float Cp[TS][4];
  __shared__ float Cq[TS][4];
  __shared__ double wred[4][5];

  const int tid = threadIdx.x;
  const int tx = tid & 15, ty = tid >> 4;
  const int lane = tid & 63, wv = tid >> 6;
  const int p0 = blockIdx.y * TS, q0 = blockIdx.x * TS;

  // stage 32 p-rows and 32 q-rows of embeddings (sample stride 6, clamp edges)
  for (int e = tid; e < TS * DIM; e += 256) {
    int r = e >> 6, k = e & 63;
    int pr = p0 + r, qr = q0 + r;
    int gp = (pr < SAMPLE ? pr : 0) * SSTRIDE;
    int gq = (qr < SAMPLE ? qr : 0) * SSTRIDE;
    Ep[r][k] = emb[(size_t)gp * DIM + k];
    Eq[r][k] = emb[(size_t)gq * DIM + k];
  }
  if (tid < TS) {
    int pr = p0 + tid;
    int g = (pr < SAMPLE ? pr : 0) * SSTRIDE;
    Cp[tid][0] = coord[3 * g]; Cp[tid][1] = coord[3 * g + 1]; Cp[tid][2] = coord[3 * g + 2];
  } else if (tid < 2 * TS) {
    int r = tid - TS;
    int qr = q0 + r;
    int g = (qr < SAMPLE ? qr : 0) * SSTRIDE;
    Cq[r][0] = coord[3 * g]; Cq[r][1] = coord[3 * g + 1]; Cq[r][2] = coord[3 * g + 2];
  }
  __syncthreads();

  // 2x2 register blocking: pairs (p0+ty+16a, q0+tx+16b)
  float s00 = 0.f, s01 = 0.f, s10 = 0.f, s11 = 0.f;
  #pragma unroll
  for (int k = 0; k < DIM; ++k) {
    float ep0 = Ep[ty][k], ep1 = Ep[ty + 16][k];
    float eq0 = Eq[tx][k], eq1 = Eq[tx + 16][k];
    float d;
    d = ep0 - eq0; s00 += d * d;
    d = ep0 - eq1; s01 += d * d;
    d = ep1 - eq0; s10 += d * d;
    d = ep1 - eq1; s11 += d * d;
  }

  double se = 0, sc = 0, se2 = 0, sc2 = 0, sec = 0;
  #pragma unroll
  for (int a = 0; a < 2; ++a) {
    #pragma unroll
    for (int b = 0; b < 2; ++b) {
      int p = p0 + ty + 16 * a, q = q0 + tx + 16 * b;
      if (p < SAMPLE && q < SAMPLE) {
        float sq = (a == 0) ? (b == 0 ? s00 : s01) : (b == 0 ? s10 : s11);
        float ed = sqrtf(fmaxf(sq, 0.f));
        float dx = Cp[ty + 16 * a][0] - Cq[tx + 16 * b][0];
        float dy = Cp[ty + 16 * a][1] - Cq[tx + 16 * b][1];
        float dz = Cp[ty + 16 * a][2] - Cq[tx + 16 * b][2];
        float cd = sqrtf(fmaxf(dx * dx + dy * dy + dz * dz, 0.f));
        se += (double)ed;
        sc += (double)cd;
        se2 += (double)ed * (double)ed;
        sc2 += (double)cd * (double)cd;
        sec += (double)ed * (double)cd;
      }
    }
  }

  // one block reduction for all 5 sums: wave butterfly then cross-wave LDS
  double vals[5] = { se, sc, se2, sc2, sec };
  #pragma unroll
  for (int v = 0; v < 5; ++v) {
    #pragma unroll
    for (int off = 32; off > 0; off >>= 1) vals[v] += __shfl_xor(vals[v], off, 64);
  }
  if (lane == 0) {
    #pragma unroll
    for (int v = 0; v < 5; ++v) wred[wv][v] = vals[v];
  }
  __syncthreads();
  if (tid < 5) {
    double s = wred[0][tid] + wred[1][tid] + wred[2][tid] + wred[3][tid];
    atomicAdd(&acc[tid], s);
  }
}

__global__ __launch_bounds__(256) void knn_kernel(
    const float* __restrict__ emb, const float* __restrict__ coord,
    double* __restrict__ acc) {
  __shared__ unsigned hist[4][256];   // per-wave histograms (4 KiB)
  __shared__ unsigned wtot[4];
  __shared__ unsigned sel[2];         // [0]=bucket, [1]=count strictly below bucket
  __shared__ int nbr[96];
  __shared__ float nd2[96];
  __shared__ unsigned ncount;
  __shared__ double wred[4];

  const int i = blockIdx.x;
  const int tid = threadIdx.x;
  const int lane = tid & 63;
  const int wv = tid >> 6;

  const float cx = coord[3 * i], cy = coord[3 * i + 1], cz = coord[3 * i + 2];

  // all 12288 squared distances, bit-cast to uint, held in 48 VGPRs/thread
  unsigned d2b[ITERS];
  #pragma unroll
  for (int it = 0; it < ITERS; ++it) {
    int j = it * 256 + tid;
    float dx = cx - coord[3 * j];
    float dy = cy - coord[3 * j + 1];
    float dz = cz - coord[3 * j + 2];
    float d2 = dx * dx + dy * dy + dz * dz;
    d2b[it] = __float_as_uint(d2);    // monotonic for d2 >= 0
  }
  const float ei = emb[(size_t)i * DIM + lane];  // lane k holds embi[k]

  // radix-select the KSEL-th smallest (4 passes of 8 bits, parallel scan)
  unsigned prefix = 0, want = KSEL;
  for (int pass = 0; pass < 4; ++pass) {
    const int shift = 24 - 8 * pass;
    const unsigned mask = pass ? (0xFFFFFFFFu << (shift + 8)) : 0u;

    for (int e = tid; e < 1024; e += 256) ((unsigned*)hist)[e] = 0;
    __syncthreads();
    unsigned* h = hist[wv];
    #pragma unroll
    for (int it = 0; it < ITERS; ++it) {
      unsigned u = d2b[it];
      if ((u & mask) == prefix) atomicAdd(&h[(u >> shift) & 0xFFu], 1u);
    }
    __syncthreads();

    // parallel select: block-wide inclusive scan over the 256 bins
    unsigned c = hist[0][tid] + hist[1][tid] + hist[2][tid] + hist[3][tid];
    unsigned incl = c;
    #pragma unroll
    for (int off = 1; off < 64; off <<= 1) {
      unsigned t2 = __shfl_up(incl, off, 64);
      if (lane >= off) incl += t2;
    }
    if (lane == 63) wtot[wv] = incl;
    __syncthreads();
    unsigned base = 0;
    for (int w = 0; w < 4; ++w) if (w < wv) base += wtot[w];
    incl += base;
    unsigned excl = incl - c;
    if (c > 0 && excl < want && want <= incl) { sel[0] = (unsigned)tid; sel[1] = excl; }
    __syncthreads();
    prefix |= sel[0] << shift;
    want -= sel[1];
  }
  // prefix == exact bit pattern of the 86th-smallest d2

  if (tid == 0) ncount = 0;
  __syncthreads();
  const unsigned thr = prefix;
  #pragma unroll
  for (int it = 0; it < ITERS; ++it) {
    int j = it * 256 + tid;
    unsigned u = d2b[it];
    if (u <= thr && j != i) {
      unsigned pos = atomicAdd(&ncount, 1u);
      if (pos < 96) { nbr[pos] = j; nd2[pos] = __uint_as_float(u); }
    }
  }
  __syncthreads();

  int m = (int)ncount; if (m > 96) m = 96;

  // cooperative loss: wave wv handles neighbors wv, wv+4, ...
  // lane k owns dim k: one coalesced 256B row load + butterfly reduce
  double lsum = 0.0;
  for (int n = wv; n < m; n += 4) {
    int j = nbr[n];
    float e = emb[(size_t)j * DIM + lane];
    float d = ei - e;
    float s = d * d;
    #pragma unroll
    for (int off = 32; off > 0; off >>= 1) s += __shfl_xor(s, off, 64);
    if (lane == 0) {
      float td = sqrtf(nd2[n]);
      float pd = sqrtf(fmaxf(s, 0.f));
      float diff = pd - td;
      lsum += (double)(diff * diff * expf(-GAMMA * td));
    }
  }
  if (lane == 0) wred[wv] = lsum;
  __syncthreads();
  if (tid == 0) atomicAdd(&acc[5], wred[0] + wred[1] + wred[2] + wred[3]);
}

__global__ void finalize_kernel(const double* __restrict__ acc,
                                float* __restrict__ out) {
  double M = (double)SAMPLE * (double)SAMPLE;
  double med = acc[0] / M, mcd = acc[1] / M;
  double ve = acc[2] / M - med * med;
  double vc = acc[3] / M - mcd * mcd;
  double es = sqrt(ve + 1e-8);
  double cs = sqrt(vc + 1e-8);
  double cov = acc[4] / M - med * mcd;
  double pearson = cov / (es * cs + 1e-8);
  double local = acc[5] / ((double)NPTS * (double)KNN);
  out[0] = (float)((1.0 - pearson) + 0.5 * local);
}

extern "C" void kernel_launch(void* const* d_in, const int* in_sizes, int n_in,
                              void* d_out, int out_size, void* d_ws, size_t ws_size,
                              hipStream_t stream) {
  const float* emb = (const float*)d_in[0];    // (12288, 64) f32
  const float* coord = (const float*)d_in[1];  // (12288, 3) f32
  double* acc = (double*)d_ws;

  hipMemsetAsync(d_ws, 0, 6 * sizeof(double), stream);

  dim3 gp((SAMPLE + TS - 1) / TS, (SAMPLE + TS - 1) / TS);  // 63 x 63
  pearson_kernel<<<gp, 256, 0, stream>>>(emb, coord, acc);

  knn_kernel<<<NPTS, 256, 0, stream>>>(emb, coord, acc);

  finalize_kernel<<<1, 1, 0, stream>>>(acc, (float*)d_out);
}

// Round 3
// 810.595 us; speedup vs baseline: 2.7942x; 1.2136x over previous
//
#include <hip/hip_runtime.h>
#include <math.h>

#define NPTS 12288
#define DIM 64
#define KNN 85
#define KSEL 86          // 85 neighbors + self
#define SAMPLE 2000
#define SSTRIDE 6        // deterministic sample: idx = 6*p, p in [0,2000)
#define GAMMA 0.5f
#define ITERS (NPTS / 256)   // 48 d2 values per thread, kept in VGPRs
#define TS 32                // pearson tile
#define LCAP 128             // per-wave candidate list capacity

// acc layout (doubles in d_ws):
// [0..4] pearson sums; [5..36] spread slots for local-loss partials

// ---- wave-local radix select: 86th-smallest among the wave's NV vals/lane ----
// h = this wave's private 256-bin LDS histogram. No __syncthreads needed:
// wave-internal LDS ordering is handled by compiler-inserted lgkmcnt waits.
template <int NV>
__device__ __forceinline__ unsigned wave_select(const unsigned v[NV], unsigned want,
                                                unsigned* h, int lane) {
  unsigned prefix = 0;
  for (int pass = 0; pass < 4; ++pass) {
    const int shift = 24 - 8 * pass;
    const unsigned hmask = pass ? (0xFFFFFFFFu << (shift + 8)) : 0u;
    h[lane] = 0; h[lane + 64] = 0; h[lane + 128] = 0; h[lane + 192] = 0;
    __builtin_amdgcn_wave_barrier();
    #pragma unroll
    for (int t = 0; t < NV; ++t) {
      unsigned u = v[t];
      if ((u & hmask) == prefix) atomicAdd(&h[(u >> shift) & 255u], 1u);
    }
    __builtin_amdgcn_wave_barrier();
    unsigned c0 = h[4 * lane], c1 = h[4 * lane + 1];
    unsigned c2 = h[4 * lane + 2], c3 = h[4 * lane + 3];
    unsigned lt = c0 + c1 + c2 + c3;
    unsigned incl = lt;
    #pragma unroll
    for (int off = 1; off < 64; off <<= 1) {
      unsigned t2 = __shfl_up(incl, off, 64);
      if (lane >= off) incl += t2;
    }
    unsigned excl = incl - lt;
    bool has = (lt > 0) && (excl < want) && (want <= incl);
    // locate bin within this lane's 4 bins (valid only on the crossing lane)
    unsigned bin = 4 * lane, below = excl, cum = excl;
    if (cum + c0 >= want) { bin = 4 * lane; below = cum; }
    else { cum += c0;
      if (cum + c1 >= want) { bin = 4 * lane + 1; below = cum; }
      else { cum += c1;
        if (cum + c2 >= want) { bin = 4 * lane + 2; below = cum; }
        else { cum += c2; bin = 4 * lane + 3; below = cum; } } }
    unsigned long long bal = __ballot(has);
    int src = __ffsll((unsigned long long)bal) - 1;
    bin = __shfl(bin, src, 64);
    below = __shfl(below, src, 64);
    prefix |= bin << shift;
    want -= below;
  }
  return prefix;
}

__global__ __launch_bounds__(256) void pearson_kernel(
    const float* __restrict__ emb, const float* __restrict__ coord,
    double* __restrict__ acc) {
  __shared__ float Ep[TS][DIM + 1];
  __shared__ float Eq[TS][DIM + 1];
  __shared__ float Cp[TS][4];
  __shared__ float Cq[TS][4];
  __shared__ double wred[4][5];

  const int tid = threadIdx.x;
  const int tx = tid & 15, ty = tid >> 4;
  const int lane = tid & 63, wv = tid >> 6;
  const int p0 = blockIdx.y * TS, q0 = blockIdx.x * TS;

  for (int e = tid; e < TS * DIM; e += 256) {
    int r = e >> 6, k = e & 63;
    int pr = p0 + r, qr = q0 + r;
    int gp = (pr < SAMPLE ? pr : 0) * SSTRIDE;
    int gq = (qr < SAMPLE ? qr : 0) * SSTRIDE;
    Ep[r][k] = emb[(size_t)gp * DIM + k];
    Eq[r][k] = emb[(size_t)gq * DIM + k];
  }
  if (tid < TS) {
    int g = (p0 + tid < SAMPLE ? p0 + tid : 0) * SSTRIDE;
    Cp[tid][0] = coord[3 * g]; Cp[tid][1] = coord[3 * g + 1]; Cp[tid][2] = coord[3 * g + 2];
  } else if (tid < 2 * TS) {
    int r = tid - TS;
    int g = (q0 + r < SAMPLE ? q0 + r : 0) * SSTRIDE;
    Cq[r][0] = coord[3 * g]; Cq[r][1] = coord[3 * g + 1]; Cq[r][2] = coord[3 * g + 2];
  }
  __syncthreads();

  float s00 = 0.f, s01 = 0.f, s10 = 0.f, s11 = 0.f;
  #pragma unroll
  for (int k = 0; k < DIM; ++k) {
    float ep0 = Ep[ty][k], ep1 = Ep[ty + 16][k];
    float eq0 = Eq[tx][k], eq1 = Eq[tx + 16][k];
    float d;
    d = ep0 - eq0; s00 += d * d;
    d = ep0 - eq1; s01 += d * d;
    d = ep1 - eq0; s10 += d * d;
    d = ep1 - eq1; s11 += d * d;
  }

  double se = 0, sc = 0, se2 = 0, sc2 = 0, sec = 0;
  #pragma unroll
  for (int a = 0; a < 2; ++a) {
    #pragma unroll
    for (int b = 0; b < 2; ++b) {
      int p = p0 + ty + 16 * a, q = q0 + tx + 16 * b;
      if (p < SAMPLE && q < SAMPLE) {
        float sq = (a == 0) ? (b == 0 ? s00 : s01) : (b == 0 ? s10 : s11);
        float ed = sqrtf(fmaxf(sq, 0.f));
        float dx = Cp[ty + 16 * a][0] - Cq[tx + 16 * b][0];
        float dy = Cp[ty + 16 * a][1] - Cq[tx + 16 * b][1];
        float dz = Cp[ty + 16 * a][2] - Cq[tx + 16 * b][2];
        float cd = sqrtf(fmaxf(dx * dx + dy * dy + dz * dz, 0.f));
        se += (double)ed; sc += (double)cd;
        se2 += (double)ed * ed; sc2 += (double)cd * cd;
        sec += (double)ed * cd;
      }
    }
  }

  double vals[5] = { se, sc, se2, sc2, sec };
  #pragma unroll
  for (int v = 0; v < 5; ++v) {
    #pragma unroll
    for (int off = 32; off > 0; off >>= 1) vals[v] += __shfl_xor(vals[v], off, 64);
  }
  if (lane == 0) {
    #pragma unroll
    for (int v = 0; v < 5; ++v) wred[wv][v] = vals[v];
  }
  __syncthreads();
  if (tid < 5) {
    double s = wred[0][tid] + wred[1][tid] + wred[2][tid] + wred[3][tid];
    atomicAdd(&acc[tid], s);
  }
}

__global__ __launch_bounds__(256, 4) void knn_kernel(
    const float* __restrict__ emb, const float* __restrict__ coord,
    double* __restrict__ acc) {
  __shared__ unsigned hist[4][256];   // per-wave private histograms
  __shared__ unsigned nbu[4][LCAP];   // per-wave candidate d2 bits
  __shared__ unsigned short nbj[4][LCAP]; // per-wave candidate indices
  __shared__ unsigned wcnt[4];
  __shared__ unsigned selg;

  const int i = blockIdx.x;
  const int tid = threadIdx.x;
  const int lane = tid & 63;
  const int wv = tid >> 6;

  const float cx = coord[3 * i], cy = coord[3 * i + 1], cz = coord[3 * i + 2];

  // 48 d2 values per thread in VGPRs (wave wv owns candidates it*256 + 64*wv + lane)
  unsigned d2b[ITERS];
  #pragma unroll
  for (int it = 0; it < ITERS; ++it) {
    int j = it * 256 + tid;
    float dx = cx - coord[3 * j];
    float dy = cy - coord[3 * j + 1];
    float dz = cz - coord[3 * j + 2];
    d2b[it] = __float_as_uint(dx * dx + dy * dy + dz * dz);
  }
  const float ei = emb[(size_t)i * DIM + lane];  // lane k holds embi[k]

  // ---- per-wave select of the wave-local 86th smallest (NO barriers) ----
  unsigned thr_w = wave_select<ITERS>(d2b, KSEL, hist[wv], lane);

  // ---- per-wave compaction of candidates u <= thr_w (ballot positions) ----
  unsigned base = 0;
  #pragma unroll
  for (int it = 0; it < ITERS; ++it) {
    unsigned u = d2b[it];
    bool p = (u <= thr_w);
    unsigned long long bm = __ballot(p);
    if (p) {
      unsigned pos = base + __popcll(bm & ((1ull << lane) - 1ull));
      if (pos < LCAP) {
        nbu[wv][pos] = u;
        nbj[wv][pos] = (unsigned short)(it * 256 + tid);
      }
    }
    base += (unsigned)__popcll(bm);
  }
  if (lane == 0) wcnt[wv] = base < LCAP ? base : LCAP;
  __syncthreads();   // barrier 1: lists visible

  // ---- wave 0 merges: exact global 86th among union of per-wave top-86 ----
  if (wv == 0) {
    unsigned mv[8];
    #pragma unroll
    for (int w = 0; w < 4; ++w) {
      unsigned mw = wcnt[w];
      mv[2 * w]     = ((unsigned)lane < mw)      ? nbu[w][lane]      : 0xFFFFFFFFu;
      mv[2 * w + 1] = ((unsigned)lane + 64 < mw) ? nbu[w][lane + 64] : 0xFFFFFFFFu;
    }
    unsigned t = wave_select<8>(mv, KSEL, hist[0], lane);
    if (lane == 0) selg = t;
  }
  __syncthreads();   // barrier 2: threshold visible
  const unsigned thrg = selg;

  // ---- loss over this wave's own list entries with u <= thrg ----
  const int mw = (int)wcnt[wv];
  double lsum = 0.0;
  #pragma unroll 2
  for (int n = 0; n < mw; ++n) {
    unsigned u = nbu[wv][n];
    int j = (int)nbj[wv][n];
    if (u <= thrg && j != i) {       // wave-uniform condition
      float e = emb[(size_t)j * DIM + lane];
      float d = ei - e;
      float s = d * d;
      #pragma unroll
      for (int off = 32; off > 0; off >>= 1) s += __shfl_xor(s, off, 64);
      float td = sqrtf(__uint_as_float(u));
      float pd = sqrtf(fmaxf(s, 0.f));
      float diff = pd - td;
      float c = diff * diff * expf(-GAMMA * td);
      if (lane == (n & 63)) lsum += (double)c;   // spread accumulation over lanes
    }
  }
  #pragma unroll
  for (int off = 32; off > 0; off >>= 1) lsum += __shfl_xor(lsum, off, 64);
  if (lane == 0) atomicAdd(&acc[5 + (blockIdx.x & 7) * 4 + wv], lsum);
}

__global__ void finalize_kernel(const double* __restrict__ acc,
                                float* __restrict__ out) {
  double M = (double)SAMPLE * (double)SAMPLE;
  double med = acc[0] / M, mcd = acc[1] / M;
  double ve = acc[2] / M - med * med;
  double vc = acc[3] / M - mcd * mcd;
  double es = sqrt(ve + 1e-8);
  double cs = sqrt(vc + 1e-8);
  double cov = acc[4] / M - med * mcd;
  double pearson = cov / (es * cs + 1e-8);
  double lsum = 0.0;
  for (int s = 5; s < 37; ++s) lsum += acc[s];
  double local = lsum / ((double)NPTS * (double)KNN);
  out[0] = (float)((1.0 - pearson) + 0.5 * local);
}

extern "C" void kernel_launch(void* const* d_in, const int* in_sizes, int n_in,
                              void* d_out, int out_size, void* d_ws, size_t ws_size,
                              hipStream_t stream) {
  const float* emb = (const float*)d_in[0];    // (12288, 64) f32
  const float* coord = (const float*)d_in[1];  // (12288, 3) f32
  double* acc = (double*)d_ws;

  hipMemsetAsync(d_ws, 0, 37 * sizeof(double), stream);

  dim3 gp((SAMPLE + TS - 1) / TS, (SAMPLE + TS - 1) / TS);  // 63 x 63
  pearson_kernel<<<gp, 256, 0, stream>>>(emb, coord, acc);

  knn_kernel<<<NPTS, 256, 0, stream>>>(emb, coord, acc);

  finalize_kernel<<<1, 1, 0, stream>>>(acc, (float*)d_out);
}

// Round 4
// 549.497 us; speedup vs baseline: 4.1218x; 1.4752x over previous
//
#include <hip/hip_runtime.h>
#include <math.h>

#define NPTS 12288
#define DIM 64
#define KNN 85
#define KSEL 86          // 85 neighbors + self
#define SAMPLE 2000
#define SSTRIDE 6        // deterministic sample: idx = 6*p, p in [0,2000)
#define GAMMA 0.5f
#define VIT 12           // float4 dist iterations: 12*256*4 = 12288
#define LCAP 128         // per-wave candidate capacity (~86-88 expected)
#define PT 64            // pearson tile
#define PPITCH 68        // padded LDS pitch (floats): 16B-aligned, 2-way-free reads

// ws layout: [0..36] double accumulators; offset 512: cx[N], cy[N], cz[N]
// acc: [0..4] pearson sums; [5..36] spread slots for local-loss partials

__global__ void prep_kernel(const float* __restrict__ coord,
                            float* __restrict__ cx, float* __restrict__ cy,
                            float* __restrict__ cz) {
  int j = blockIdx.x * 256 + threadIdx.x;
  if (j < NPTS) {
    cx[j] = coord[3 * j];
    cy[j] = coord[3 * j + 1];
    cz[j] = coord[3 * j + 2];
  }
}

// wave-local radix select over NV values/lane; PASSES=2 returns an inclusive
// upper-edge threshold (16-bit bucket); PASSES=4 returns the exact k-th value.
// h = this wave's private 256-bin histogram (wave-internal DS ordering only).
template <int NV, int PASSES>
__device__ __forceinline__ unsigned wave_select(const unsigned v[NV], unsigned want,
                                                unsigned* h, int lane) {
  unsigned prefix = 0;
  #pragma unroll
  for (int pass = 0; pass < PASSES; ++pass) {
    const int shift = 24 - 8 * pass;
    const unsigned hmask = pass ? (0xFFFFFFFFu << (shift + 8)) : 0u;
    h[lane] = 0; h[lane + 64] = 0; h[lane + 128] = 0; h[lane + 192] = 0;
    __builtin_amdgcn_wave_barrier();
    #pragma unroll
    for (int t = 0; t < NV; ++t) {
      unsigned u = v[t];
      if ((u & hmask) == prefix) atomicAdd(&h[(u >> shift) & 255u], 1u);
    }
    __builtin_amdgcn_wave_barrier();
    unsigned c0 = h[4 * lane], c1 = h[4 * lane + 1];
    unsigned c2 = h[4 * lane + 2], c3 = h[4 * lane + 3];
    unsigned lt = c0 + c1 + c2 + c3;
    unsigned incl = lt;
    #pragma unroll
    for (int off = 1; off < 64; off <<= 1) {
      unsigned t2 = __shfl_up(incl, off, 64);
      if (lane >= off) incl += t2;
    }
    unsigned excl = incl - lt;
    bool has = (lt > 0) && (excl < want) && (want <= incl);
    unsigned bin = 4 * lane, below = excl, cum = excl;
    if (cum + c0 >= want) { bin = 4 * lane; below = cum; }
    else { cum += c0;
      if (cum + c1 >= want) { bin = 4 * lane + 1; below = cum; }
      else { cum += c1;
        if (cum + c2 >= want) { bin = 4 * lane + 2; below = cum; }
        else { cum += c2; bin = 4 * lane + 3; below = cum; } } }
    unsigned long long bal = __ballot(has);
    int src = __ffsll((unsigned long long)bal) - 1;
    bin = __shfl(bin, src, 64);
    below = __shfl(below, src, 64);
    prefix |= bin << shift;
    want -= below;
  }
  return (PASSES == 4) ? prefix : (prefix | (0xFFFFFFFFu >> (8 * PASSES)));
}

__global__ __launch_bounds__(256) void pearson_kernel(
    const float* __restrict__ emb, const float* __restrict__ coord,
    double* __restrict__ acc) {
  __shared__ float EpT[DIM][PPITCH];   // transposed: EpT[k][row]
  __shared__ float EqT[DIM][PPITCH];
  __shared__ float Cp[PT][4];
  __shared__ float Cq[PT][4];
  __shared__ double wred[4][5];

  const int tid = threadIdx.x;
  const int tx = tid & 15, ty = tid >> 4;
  const int lane = tid & 63, wv = tid >> 6;
  const int p0 = blockIdx.y * PT, q0 = blockIdx.x * PT;

  // stage transposed (coalesced global reads; 8-way LDS write aliasing accepted)
  for (int e = tid; e < PT * DIM; e += 256) {
    int r = e >> 6, k = e & 63;
    int gp = (p0 + r < SAMPLE ? p0 + r : 0) * SSTRIDE;
    int gq = (q0 + r < SAMPLE ? q0 + r : 0) * SSTRIDE;
    EpT[k][r] = emb[(size_t)gp * DIM + k];
    EqT[k][r] = emb[(size_t)gq * DIM + k];
  }
  if (tid < PT) {
    int g = (p0 + tid < SAMPLE ? p0 + tid : 0) * SSTRIDE;
    Cp[tid][0] = coord[3 * g]; Cp[tid][1] = coord[3 * g + 1]; Cp[tid][2] = coord[3 * g + 2];
  } else if (tid < 2 * PT) {
    int r = tid - PT;
    int g = (q0 + r < SAMPLE ? q0 + r : 0) * SSTRIDE;
    Cq[r][0] = coord[3 * g]; Cq[r][1] = coord[3 * g + 1]; Cq[r][2] = coord[3 * g + 2];
  }
  __syncthreads();

  // 4x4 register blocking: p = p0+4ty+a, q = q0+4tx+b
  float s[4][4] = {};
  #pragma unroll 8
  for (int k = 0; k < DIM; ++k) {
    float4 ep = *(const float4*)&EpT[k][4 * ty];   // b128, 16-way broadcast
    float4 eq = *(const float4*)&EqT[k][4 * tx];   // b128, 2-way free
    float pa[4] = { ep.x, ep.y, ep.z, ep.w };
    float qa[4] = { eq.x, eq.y, eq.z, eq.w };
    #pragma unroll
    for (int a = 0; a < 4; ++a)
      #pragma unroll
      for (int b = 0; b < 4; ++b) {
        float d = pa[a] - qa[b];
        s[a][b] += d * d;
      }
  }

  double se = 0, sc = 0, se2 = 0, sc2 = 0, sec = 0;
  #pragma unroll
  for (int a = 0; a < 4; ++a)
    #pragma unroll
    for (int b = 0; b < 4; ++b) {
      int p = p0 + 4 * ty + a, q = q0 + 4 * tx + b;
      if (p < SAMPLE && q < SAMPLE) {
        float ed = sqrtf(fmaxf(s[a][b], 0.f));
        float dx = Cp[4 * ty + a][0] - Cq[4 * tx + b][0];
        float dy = Cp[4 * ty + a][1] - Cq[4 * tx + b][1];
        float dz = Cp[4 * ty + a][2] - Cq[4 * tx + b][2];
        float cd = sqrtf(fmaxf(dx * dx + dy * dy + dz * dz, 0.f));
        se += (double)ed; sc += (double)cd;
        se2 += (double)ed * ed; sc2 += (double)cd * cd;
        sec += (double)ed * cd;
      }
    }

  double vals[5] = { se, sc, se2, sc2, sec };
  #pragma unroll
  for (int v = 0; v < 5; ++v) {
    #pragma unroll
    for (int off = 32; off > 0; off >>= 1) vals[v] += __shfl_xor(vals[v], off, 64);
  }
  if (lane == 0) {
    #pragma unroll
    for (int v = 0; v < 5; ++v) wred[wv][v] = vals[v];
  }
  __syncthreads();
  if (tid < 5) {
    double sm = wred[0][tid] + wred[1][tid] + wred[2][tid] + wred[3][tid];
    atomicAdd(&acc[tid], sm);
  }
}

__global__ __launch_bounds__(256) void knn_kernel(
    const float* __restrict__ emb, const float* __restrict__ cx,
    const float* __restrict__ cy, const float* __restrict__ cz,
    double* __restrict__ acc) {
  __shared__ unsigned hist[4][256];
  __shared__ unsigned nbu[4][LCAP];
  __shared__ unsigned short nbj[4][LCAP];
  __shared__ unsigned wcnt[4];
  __shared__ unsigned selg;

  const int i = blockIdx.x;
  const int tid = threadIdx.x;
  const int lane = tid & 63;
  const int wv = tid >> 6;

  const float qx = cx[i], qy = cy[i], qz = cz[i];
  const float4* CX4 = (const float4*)cx;
  const float4* CY4 = (const float4*)cy;
  const float4* CZ4 = (const float4*)cz;

  // 48 d2 values per thread (float4 coord streams), bit-cast to uint in VGPRs
  unsigned d2b[4 * VIT];
  #pragma unroll
  for (int it = 0; it < VIT; ++it) {
    int idx = it * 256 + tid;
    float4 x4 = CX4[idx], y4 = CY4[idx], z4 = CZ4[idx];
    float dx, dy, dz;
    dx = qx - x4.x; dy = qy - y4.x; dz = qz - z4.x;
    d2b[4 * it + 0] = __float_as_uint(dx * dx + dy * dy + dz * dz);
    dx = qx - x4.y; dy = qy - y4.y; dz = qz - z4.y;
    d2b[4 * it + 1] = __float_as_uint(dx * dx + dy * dy + dz * dz);
    dx = qx - x4.z; dy = qy - y4.z; dz = qz - z4.z;
    d2b[4 * it + 2] = __float_as_uint(dx * dx + dy * dy + dz * dz);
    dx = qx - x4.w; dy = qy - y4.w; dz = qz - z4.w;
    d2b[4 * it + 3] = __float_as_uint(dx * dx + dy * dy + dz * dz);
  }
  // lane's embedding chunk for the quarter-lane loss scheme
  const float4 ei4 = ((const float4*)(emb + (size_t)i * DIM))[lane & 15];

  // 2-pass coarse select: inclusive upper bound on the wave-local 86th
  unsigned U = wave_select<4 * VIT, 2>(d2b, KSEL, hist[wv], lane);

  // guarded atomic append of candidates (expected ~86-88 per wave)
  if (lane == 0) wcnt[wv] = 0;
  __builtin_amdgcn_wave_barrier();
  #pragma unroll
  for (int it = 0; it < VIT; ++it) {
    #pragma unroll
    for (int c = 0; c < 4; ++c) {
      unsigned u = d2b[4 * it + c];
      if (u <= U) {
        unsigned pos = atomicAdd(&wcnt[wv], 1u);
        if (pos < LCAP) {
          nbu[wv][pos] = u;
          nbj[wv][pos] = (unsigned short)(4 * (it * 256 + tid) + c);
        }
      }
    }
  }
  __syncthreads();   // barrier 1: lists visible

  // wave 0: exact global 86th among the union (each wave's list covers its top-86)
  if (wv == 0) {
    unsigned mv[8];
    #pragma unroll
    for (int w = 0; w < 4; ++w) {
      unsigned mw = wcnt[w] < LCAP ? wcnt[w] : LCAP;
      mv[2 * w]     = ((unsigned)lane < mw)      ? nbu[w][lane]      : 0xFFFFFFFFu;
      mv[2 * w + 1] = ((unsigned)lane + 64 < mw) ? nbu[w][lane + 64] : 0xFFFFFFFFu;
    }
    unsigned t = wave_select<8, 4>(mv, KSEL, hist[0], lane);
    if (lane == 0) selg = t;
  }
  __syncthreads();   // barrier 2: threshold visible
  const unsigned thrg = selg;

  // loss: 4 neighbors per wave-iteration; quarter q owns neighbor n+q
  const int mw = (int)(wcnt[wv] < LCAP ? wcnt[wv] : LCAP);
  const int q = lane >> 4;
  const int l16 = lane & 15;
  float lsum = 0.f;
  for (int n = 0; n < mw; n += 4) {
    int idx = n + q;
    bool valid = false; unsigned u = 0; int j = 0;
    if (idx < mw) {
      u = nbu[wv][idx];
      j = (int)nbj[wv][idx];
      valid = (u <= thrg) && (j != i);
    }
    float s = 0.f;
    if (valid) {
      float4 e4 = ((const float4*)(emb + (size_t)j * DIM))[l16];
      float d0 = ei4.x - e4.x, d1 = ei4.y - e4.y;
      float d2 = ei4.z - e4.z, d3 = ei4.w - e4.w;
      s = d0 * d0 + d1 * d1 + d2 * d2 + d3 * d3;
    }
    s += __shfl_xor(s, 1, 64);
    s += __shfl_xor(s, 2, 64);
    s += __shfl_xor(s, 4, 64);
    s += __shfl_xor(s, 8, 64);
    if (valid && l16 == 0) {
      float td = sqrtf(__uint_as_float(u));
      float pd = sqrtf(fmaxf(s, 0.f));
      float diff = pd - td;
      lsum += diff * diff * expf(-GAMMA * td);
    }
  }
  #pragma unroll
  for (int off = 32; off > 0; off >>= 1) lsum += __shfl_xor(lsum, off, 64);
  if (lane == 0) atomicAdd(&acc[5 + (blockIdx.x & 7) * 4 + wv], (double)lsum);
}

__global__ void finalize_kernel(const double* __restrict__ acc,
                                float* __restrict__ out) {
  double M = (double)SAMPLE * (double)SAMPLE;
  double med = acc[0] / M, mcd = acc[1] / M;
  double ve = acc[2] / M - med * med;
  double vc = acc[3] / M - mcd * mcd;
  double es = sqrt(ve + 1e-8);
  double cs = sqrt(vc + 1e-8);
  double cov = acc[4] / M - med * mcd;
  double pearson = cov / (es * cs + 1e-8);
  double lsum = 0.0;
  for (int s = 5; s < 37; ++s) lsum += acc[s];
  double local = lsum / ((double)NPTS * (double)KNN);
  out[0] = (float)((1.0 - pearson) + 0.5 * local);
}

extern "C" void kernel_launch(void* const* d_in, const int* in_sizes, int n_in,
                              void* d_out, int out_size, void* d_ws, size_t ws_size,
                              hipStream_t stream) {
  const float* emb = (const float*)d_in[0];    // (12288, 64) f32
  const float* coord = (const float*)d_in[1];  // (12288, 3) f32
  double* acc = (double*)d_ws;
  float* cx = (float*)((char*)d_ws + 512);     // 16B-aligned SoA coords
  float* cy = cx + NPTS;
  float* cz = cy + NPTS;

  hipMemsetAsync(d_ws, 0, 37 * sizeof(double), stream);

  prep_kernel<<<(NPTS + 255) / 256, 256, 0, stream>>>(coord, cx, cy, cz);

  dim3 gp(PT / 2, PT / 2);  // 32 x 32 blocks of 64x64 pairs (2048 >= 2000)
  pearson_kernel<<<dim3((SAMPLE + PT - 1) / PT, (SAMPLE + PT - 1) / PT), 256, 0, stream>>>(
      emb, coord, acc);

  knn_kernel<<<NPTS, 256, 0, stream>>>(emb, cx, cy, cz, acc);

  finalize_kernel<<<1, 1, 0, stream>>>(acc, (float*)d_out);
}

// Round 5
// 453.183 us; speedup vs baseline: 4.9978x; 1.2125x over previous
//
#include <hip/hip_runtime.h>
#include <math.h>

#define NPTS 12288
#define DIM 64
#define KNN 85
#define KSEL 86          // 85 neighbors + self
#define SAMPLE 2000
#define SSTRIDE 6        // deterministic sample: idx = 6*p, p in [0,2000)
#define GAMMA 0.5f
#define VIT 12           // float4 dist iterations: 12*256*4 = 12288
#define LCAP 128         // per-wave candidate capacity (~87-90 expected)
#define PT 64            // pearson tile
#define PPITCH 68        // padded LDS pitch (floats)

// ws layout: [0..36] double accumulators; offset 512: cx[N], cy[N], cz[N]
// acc: [0..4] pearson sums; [5..36] spread slots for local-loss partials

__global__ void prep_kernel(const float* __restrict__ coord,
                            float* __restrict__ cx, float* __restrict__ cy,
                            float* __restrict__ cz) {
  int j = blockIdx.x * 256 + threadIdx.x;
  if (j < NPTS) {
    cx[j] = coord[3 * j];
    cy[j] = coord[3 * j + 1];
    cz[j] = coord[3 * j + 2];
  }
}

// exact wave-local radix select (4x8-bit passes) -- used only for the merge
// over <=512 candidates on wave 0. h = wave-private 256-bin LDS histogram.
template <int NV>
__device__ __forceinline__ unsigned wave_select4(const unsigned v[NV], unsigned want,
                                                 unsigned* h, int lane) {
  unsigned prefix = 0;
  #pragma unroll
  for (int pass = 0; pass < 4; ++pass) {
    const int shift = 24 - 8 * pass;
    const unsigned hmask = pass ? (0xFFFFFFFFu << (shift + 8)) : 0u;
    h[lane] = 0; h[lane + 64] = 0; h[lane + 128] = 0; h[lane + 192] = 0;
    __builtin_amdgcn_wave_barrier();
    #pragma unroll
    for (int t = 0; t < NV; ++t) {
      unsigned u = v[t];
      if ((u & hmask) == prefix) atomicAdd(&h[(u >> shift) & 255u], 1u);
    }
    __builtin_amdgcn_wave_barrier();
    unsigned c0 = h[4 * lane], c1 = h[4 * lane + 1];
    unsigned c2 = h[4 * lane + 2], c3 = h[4 * lane + 3];
    unsigned lt = c0 + c1 + c2 + c3;
    unsigned incl = lt;
    #pragma unroll
    for (int off = 1; off < 64; off <<= 1) {
      unsigned t2 = __shfl_up(incl, off, 64);
      if (lane >= off) incl += t2;
    }
    unsigned excl = incl - lt;
    bool has = (lt > 0) && (excl < want) && (want <= incl);
    unsigned bin = 4 * lane, below = excl, cum = excl;
    if (cum + c0 >= want) { bin = 4 * lane; below = cum; }
    else { cum += c0;
      if (cum + c1 >= want) { bin = 4 * lane + 1; below = cum; }
      else { cum += c1;
        if (cum + c2 >= want) { bin = 4 * lane + 2; below = cum; }
        else { cum += c2; bin = 4 * lane + 3; below = cum; } } }
    unsigned long long bal = __ballot(has);
    int src = __ffsll((unsigned long long)bal) - 1;
    bin = __shfl(bin, src, 64);
    below = __shfl(below, src, 64);
    prefix |= bin << shift;
    want -= below;
  }
  return prefix;
}

__global__ __launch_bounds__(256) void pearson_kernel(
    const float* __restrict__ emb, const float* __restrict__ coord,
    double* __restrict__ acc) {
  __shared__ float EpT[DIM][PPITCH];   // transposed: EpT[k][row]
  __shared__ float EqT[DIM][PPITCH];
  __shared__ float Cp[PT][4];
  __shared__ float Cq[PT][4];
  __shared__ double wred[4][5];

  const int tid = threadIdx.x;
  const int tx = tid & 15, ty = tid >> 4;
  const int lane = tid & 63, wv = tid >> 6;
  const int p0 = blockIdx.y * PT, q0 = blockIdx.x * PT;

  for (int e = tid; e < PT * DIM; e += 256) {
    int r = e >> 6, k = e & 63;
    int gp = (p0 + r < SAMPLE ? p0 + r : 0) * SSTRIDE;
    int gq = (q0 + r < SAMPLE ? q0 + r : 0) * SSTRIDE;
    EpT[k][r] = emb[(size_t)gp * DIM + k];
    EqT[k][r] = emb[(size_t)gq * DIM + k];
  }
  if (tid < PT) {
    int g = (p0 + tid < SAMPLE ? p0 + tid : 0) * SSTRIDE;
    Cp[tid][0] = coord[3 * g]; Cp[tid][1] = coord[3 * g + 1]; Cp[tid][2] = coord[3 * g + 2];
  } else if (tid < 2 * PT) {
    int r = tid - PT;
    int g = (q0 + r < SAMPLE ? q0 + r : 0) * SSTRIDE;
    Cq[r][0] = coord[3 * g]; Cq[r][1] = coord[3 * g + 1]; Cq[r][2] = coord[3 * g + 2];
  }
  __syncthreads();

  float s[4][4] = {};
  #pragma unroll 8
  for (int k = 0; k < DIM; ++k) {
    float4 ep = *(const float4*)&EpT[k][4 * ty];
    float4 eq = *(const float4*)&EqT[k][4 * tx];
    float pa[4] = { ep.x, ep.y, ep.z, ep.w };
    float qa[4] = { eq.x, eq.y, eq.z, eq.w };
    #pragma unroll
    for (int a = 0; a < 4; ++a)
      #pragma unroll
      for (int b = 0; b < 4; ++b) {
        float d = pa[a] - qa[b];
        s[a][b] += d * d;
      }
  }

  double se = 0, sc = 0, se2 = 0, sc2 = 0, sec = 0;
  #pragma unroll
  for (int a = 0; a < 4; ++a)
    #pragma unroll
    for (int b = 0; b < 4; ++b) {
      int p = p0 + 4 * ty + a, q = q0 + 4 * tx + b;
      if (p < SAMPLE && q < SAMPLE) {
        float ed = sqrtf(fmaxf(s[a][b], 0.f));
        float dx = Cp[4 * ty + a][0] - Cq[4 * tx + b][0];
        float dy = Cp[4 * ty + a][1] - Cq[4 * tx + b][1];
        float dz = Cp[4 * ty + a][2] - Cq[4 * tx + b][2];
        float cd = sqrtf(fmaxf(dx * dx + dy * dy + dz * dz, 0.f));
        se += (double)ed; sc += (double)cd;
        se2 += (double)ed * ed; sc2 += (double)cd * cd;
        sec += (double)ed * cd;
      }
    }

  double vals[5] = { se, sc, se2, sc2, sec };
  #pragma unroll
  for (int v = 0; v < 5; ++v) {
    #pragma unroll
    for (int off = 32; off > 0; off >>= 1) vals[v] += __shfl_xor(vals[v], off, 64);
  }
  if (lane == 0) {
    #pragma unroll
    for (int v = 0; v < 5; ++v) wred[wv][v] = vals[v];
  }
  __syncthreads();
  if (tid < 5) {
    double sm = wred[0][tid] + wred[1][tid] + wred[2][tid] + wred[3][tid];
    atomicAdd(&acc[tid], sm);
  }
}

__global__ __launch_bounds__(256) void knn_kernel(
    const float* __restrict__ emb, const float* __restrict__ cx,
    const float* __restrict__ cy, const float* __restrict__ cz,
    double* __restrict__ acc) {
  __shared__ unsigned hist[4][256];
  __shared__ unsigned nbu[4][LCAP];
  __shared__ unsigned short nbj[4][LCAP];
  __shared__ unsigned wcnt[4];
  __shared__ unsigned selg;

  const int i = blockIdx.x;
  const int tid = threadIdx.x;
  const int lane = tid & 63;
  const int wv = tid >> 6;

  const float qx = cx[i], qy = cy[i], qz = cz[i];
  const float4* CX4 = (const float4*)cx;
  const float4* CY4 = (const float4*)cy;
  const float4* CZ4 = (const float4*)cz;

  // 48 d2 values per thread (float4 coord streams), bit-cast to uint in VGPRs
  unsigned d2b[4 * VIT];
  #pragma unroll
  for (int it = 0; it < VIT; ++it) {
    int idx = it * 256 + tid;
    float4 x4 = CX4[idx], y4 = CY4[idx], z4 = CZ4[idx];
    float dx, dy, dz;
    dx = qx - x4.x; dy = qy - y4.x; dz = qz - z4.x;
    d2b[4 * it + 0] = __float_as_uint(dx * dx + dy * dy + dz * dz);
    dx = qx - x4.y; dy = qy - y4.y; dz = qz - z4.y;
    d2b[4 * it + 1] = __float_as_uint(dx * dx + dy * dy + dz * dz);
    dx = qx - x4.z; dy = qy - y4.z; dz = qz - z4.z;
    d2b[4 * it + 2] = __float_as_uint(dx * dx + dy * dy + dz * dz);
    dx = qx - x4.w; dy = qy - y4.w; dz = qz - z4.w;
    d2b[4 * it + 3] = __float_as_uint(dx * dx + dy * dy + dz * dz);
  }
  const float4 ei4 = ((const float4*)(emb + (size_t)i * DIM))[lane & 15];

  // ---- VALU pre-filter: per-lane two smallest (uint order == float order) ----
  unsigned m1 = 0xFFFFFFFFu, m2 = 0xFFFFFFFFu;
  #pragma unroll
  for (int t = 0; t < 4 * VIT; ++t) {
    unsigned u = d2b[t];
    unsigned hi = u > m1 ? u : m1;       // max(u, m1_old)
    m1 = u < m1 ? u : m1;                // min
    m2 = hi < m2 ? hi : m2;              // min(m2, max(u, m1_old))
  }
  // M2 = wave-max of 2nd-smallest: >=128 values <= M2, so wave-86th <= M2
  unsigned M2 = m2;
  #pragma unroll
  for (int off = 32; off > 0; off >>= 1) {
    unsigned t2 = __shfl_xor((int)M2, off, 64);
    M2 = t2 > M2 ? t2 : M2;
  }
  const float M2f = __uint_as_float(M2);
  const float sbin = 256.0f / fmaxf(M2f, 1e-30f);

  // ---- single linear-binned histogram over filtered values (~6 atomics/lane) --
  unsigned* h = hist[wv];
  h[lane] = 0; h[lane + 64] = 0; h[lane + 128] = 0; h[lane + 192] = 0;
  __builtin_amdgcn_wave_barrier();
  #pragma unroll
  for (int t = 0; t < 4 * VIT; ++t) {
    unsigned u = d2b[t];
    if (u <= M2) {
      int b = (int)(__uint_as_float(u) * sbin);
      b = b > 255 ? 255 : b;
      atomicAdd(&h[b], 1u);
    }
  }
  __builtin_amdgcn_wave_barrier();
  unsigned c0 = h[4 * lane], c1 = h[4 * lane + 1];
  unsigned c2 = h[4 * lane + 2], c3 = h[4 * lane + 3];
  unsigned lt = c0 + c1 + c2 + c3;
  unsigned incl = lt;
  #pragma unroll
  for (int off = 1; off < 64; off <<= 1) {
    unsigned t2 = __shfl_up(incl, off, 64);
    if (lane >= off) incl += t2;
  }
  unsigned excl = incl - lt;
  bool has = (lt > 0) && (excl < KSEL) && (KSEL <= incl);
  unsigned bin = 4 * lane, cum = excl;
  if (cum + c0 >= KSEL) { bin = 4 * lane; }
  else { cum += c0;
    if (cum + c1 >= KSEL) { bin = 4 * lane + 1; }
    else { cum += c1;
      if (cum + c2 >= KSEL) { bin = 4 * lane + 2; }
      else { bin = 4 * lane + 3; } } }
  unsigned long long bal = __ballot(has);
  int src = __ffsll((unsigned long long)bal) - 1;
  unsigned bsel = __shfl((int)bin, src, 64);
  // inclusive upper edge of the selected bucket (2-ulp safety margin up)
  float Uf = (float)(bsel + 1) * (M2f * (1.0f / 256.0f)) * 1.000002f;
  unsigned U = __float_as_uint(Uf);

  // ---- guarded atomic append of candidates u <= U (~87-90 per wave) ----
  if (lane == 0) wcnt[wv] = 0;
  __builtin_amdgcn_wave_barrier();
  #pragma unroll
  for (int it = 0; it < VIT; ++it) {
    #pragma unroll
    for (int c = 0; c < 4; ++c) {
      unsigned u = d2b[4 * it + c];
      if (u <= U) {
        unsigned pos = atomicAdd(&wcnt[wv], 1u);
        if (pos < LCAP) {
          nbu[wv][pos] = u;
          nbj[wv][pos] = (unsigned short)(4 * (it * 256 + tid) + c);
        }
      }
    }
  }
  __syncthreads();   // barrier 1: lists visible

  // ---- wave 0: exact global 86th among the union of per-wave candidate sets --
  if (wv == 0) {
    unsigned mv[8];
    #pragma unroll
    for (int w = 0; w < 4; ++w) {
      unsigned mw = wcnt[w] < LCAP ? wcnt[w] : LCAP;
      mv[2 * w]     = ((unsigned)lane < mw)      ? nbu[w][lane]      : 0xFFFFFFFFu;
      mv[2 * w + 1] = ((unsigned)lane + 64 < mw) ? nbu[w][lane + 64] : 0xFFFFFFFFu;
    }
    unsigned t = wave_select4<8>(mv, KSEL, hist[0], lane);
    if (lane == 0) selg = t;
  }
  __syncthreads();   // barrier 2: threshold visible
  const unsigned thrg = selg;

  // ---- loss: 4 neighbors per wave-iteration; quarter q owns neighbor n+q ----
  const int mw = (int)(wcnt[wv] < LCAP ? wcnt[wv] : LCAP);
  const int q = lane >> 4;
  const int l16 = lane & 15;
  float lsum = 0.f;
  for (int n = 0; n < mw; n += 4) {
    int idx = n + q;
    bool valid = false; unsigned u = 0; int j = 0;
    if (idx < mw) {
      u = nbu[wv][idx];
      j = (int)nbj[wv][idx];
      valid = (u <= thrg) && (j != i);
    }
    float s = 0.f;
    if (valid) {
      float4 e4 = ((const float4*)(emb + (size_t)j * DIM))[l16];
      float d0 = ei4.x - e4.x, d1 = ei4.y - e4.y;
      float d2 = ei4.z - e4.z, d3 = ei4.w - e4.w;
      s = d0 * d0 + d1 * d1 + d2 * d2 + d3 * d3;
    }
    s += __shfl_xor(s, 1, 64);
    s += __shfl_xor(s, 2, 64);
    s += __shfl_xor(s, 4, 64);
    s += __shfl_xor(s, 8, 64);
    if (valid && l16 == 0) {
      float td = sqrtf(__uint_as_float(u));
      float pd = sqrtf(fmaxf(s, 0.f));
      float diff = pd - td;
      lsum += diff * diff * expf(-GAMMA * td);
    }
  }
  #pragma unroll
  for (int off = 32; off > 0; off >>= 1) lsum += __shfl_xor(lsum, off, 64);
  if (lane == 0) atomicAdd(&acc[5 + (blockIdx.x & 7) * 4 + wv], (double)lsum);
}

__global__ void finalize_kernel(const double* __restrict__ acc,
                                float* __restrict__ out) {
  double M = (double)SAMPLE * (double)SAMPLE;
  double med = acc[0] / M, mcd = acc[1] / M;
  double ve = acc[2] / M - med * med;
  double vc = acc[3] / M - mcd * mcd;
  double es = sqrt(ve + 1e-8);
  double cs = sqrt(vc + 1e-8);
  double cov = acc[4] / M - med * mcd;
  double pearson = cov / (es * cs + 1e-8);
  double lsum = 0.0;
  for (int s = 5; s < 37; ++s) lsum += acc[s];
  double local = lsum / ((double)NPTS * (double)KNN);
  out[0] = (float)((1.0 - pearson) + 0.5 * local);
}

extern "C" void kernel_launch(void* const* d_in, const int* in_sizes, int n_in,
                              void* d_out, int out_size, void* d_ws, size_t ws_size,
                              hipStream_t stream) {
  const float* emb = (const float*)d_in[0];    // (12288, 64) f32
  const float* coord = (const float*)d_in[1];  // (12288, 3) f32
  double* acc = (double*)d_ws;
  float* cx = (float*)((char*)d_ws + 512);     // 16B-aligned SoA coords
  float* cy = cx + NPTS;
  float* cz = cy + NPTS;

  hipMemsetAsync(d_ws, 0, 37 * sizeof(double), stream);

  prep_kernel<<<(NPTS + 255) / 256, 256, 0, stream>>>(coord, cx, cy, cz);

  pearson_kernel<<<dim3((SAMPLE + PT - 1) / PT, (SAMPLE + PT - 1) / PT), 256, 0, stream>>>(
      emb, coord, acc);

  knn_kernel<<<NPTS, 256, 0, stream>>>(emb, cx, cy, cz, acc);

  finalize_kernel<<<1, 1, 0, stream>>>(acc, (float*)d_out);
}